// Round 15
// baseline (69.319 us; speedup 1.0000x reference)
//
#include <hip/hip_runtime.h>
#include <hip/hip_bf16.h>

#define B_ 8
#define S_ 2048
#define E_ 1024
#define H_ 64
#define LOG2E 1.4426950408889634f

typedef __attribute__((ext_vector_type(8))) short short8;
typedef __attribute__((ext_vector_type(4))) float floatx4;
typedef unsigned int u32;

static __device__ __forceinline__ short f2bf(float f) {
    union { float f; unsigned u; } a; a.f = f;
    unsigned r = a.u + 0x7FFF + ((a.u >> 16) & 1);
    return (short)(r >> 16);
}
static __device__ __forceinline__ float bf2f(short s) {
    union { unsigned u; float f; } a; a.u = ((u32)(unsigned short)s) << 16;
    return a.f;
}
static __device__ __forceinline__ void gl_lds16(const void* g, void* l) {
    __builtin_amdgcn_global_load_lds(
        (const __attribute__((address_space(1))) u32*)(g),
        (__attribute__((address_space(3))) u32*)(l),
        16, 0, 0);
}

// ---------------------------------------------------------------------------
// Kernel 1: weights -> bf16, tiled per K-panel [16][192][64] with XOR chunk
// swizzle pre-applied in global.
// ---------------------------------------------------------------------------
__global__ __launch_bounds__(256) void wprep_kernel(
        const float* __restrict__ wq, const float* __restrict__ wk,
        const float* __restrict__ wv, short* __restrict__ Wt) {
    __shared__ short Ws[64][73];
    int bid = blockIdx.x;
    int m  = bid >> 4;
    int ec = bid & 15;
    const float* src = (m == 0) ? wq : ((m == 1) ? wk : wv);
    int t = threadIdx.x;
    {
        int er = t >> 2;
        int hc = (t & 3) * 16;
        const float* sp = src + (size_t)(ec * 64 + er) * H_ + hc;
        floatx4 v0 = *(const floatx4*)(sp);
        floatx4 v1 = *(const floatx4*)(sp + 4);
        floatx4 v2 = *(const floatx4*)(sp + 8);
        floatx4 v3 = *(const floatx4*)(sp + 12);
#pragma unroll
        for (int j = 0; j < 4; j++) Ws[er][hc + j]      = f2bf(v0[j]);
#pragma unroll
        for (int j = 0; j < 4; j++) Ws[er][hc + 4 + j]  = f2bf(v1[j]);
#pragma unroll
        for (int j = 0; j < 4; j++) Ws[er][hc + 8 + j]  = f2bf(v2[j]);
#pragma unroll
        for (int j = 0; j < 4; j++) Ws[er][hc + 12 + j] = f2bf(v3[j]);
    }
    __syncthreads();
    {
        int h  = t >> 2;
        int eo = (t & 3) * 16;
        int row = m * 64 + h;
        short* obase = Wt + (size_t)ec * 12288 + (size_t)row * 64;
#pragma unroll
        for (int g = 0; g < 2; g++) {
            short8 o;
#pragma unroll
            for (int jj = 0; jj < 8; jj++) o[jj] = Ws[eo + g * 8 + jj][h];
            int chunk = ((eo >> 3) + g) ^ (row & 7);
            *(short8*)(obase + chunk * 8) = o;
        }
    }
}

// ---------------------------------------------------------------------------
// Kernel 2: QKV projection GEMM (r10 version — best measured).
// BK=128, BM=64, grid 256, 512 thr = 8 waves (2 row x 4 col).
// ---------------------------------------------------------------------------
struct StageRegs {
    floatx4 x0, x1, x2, x3;
    short8 w0, w1, w2, w3, w4, w5;
};

__global__ __launch_bounds__(512, 2) void qkv_proj_kernel(
        const float* __restrict__ x, const short* __restrict__ Wt,
        short* __restrict__ qb, short* __restrict__ kb, short* __restrict__ vb) {
    __shared__ __align__(16) short Wlds[2][24576];
    __shared__ __align__(16) short Xlds[2][8704];

    int tid  = threadIdx.x;
    int lane = tid & 63;
    int w    = tid >> 6;
    int lrow = lane & 15;
    int lgrp = lane >> 4;

    int wr = w & 1;
    int wc = w >> 1;
    int rowbase = blockIdx.x * 64;

    int xr = tid >> 3;
    int xc = tid & 7;
    const float* xgp = x + (size_t)(rowbase + xr) * E_ + xc * 16;
    const short* wgp = Wt + (size_t)tid * 8;

    floatx4 acc0[3], acc1[3];
#pragma unroll
    for (int i = 0; i < 3; i++) {
        acc0[i] = (floatx4){0.f, 0.f, 0.f, 0.f};
        acc1[i] = (floatx4){0.f, 0.f, 0.f, 0.f};
    }

    StageRegs A, B;

#define LOADST(R, S) do {                                                    \
        const float* xn = xgp + (S) * 128;                                   \
        R.x0 = *(const floatx4*)(xn);                                        \
        R.x1 = *(const floatx4*)(xn + 4);                                    \
        R.x2 = *(const floatx4*)(xn + 8);                                    \
        R.x3 = *(const floatx4*)(xn + 12);                                   \
        const short* wn = wgp + (size_t)(S) * 24576;                         \
        R.w0 = *(const short8*)(wn);                                         \
        R.w1 = *(const short8*)(wn + 4096);                                  \
        R.w2 = *(const short8*)(wn + 8192);                                  \
        R.w3 = *(const short8*)(wn + 12288);                                 \
        R.w4 = *(const short8*)(wn + 16384);                                 \
        R.w5 = *(const short8*)(wn + 20480);                                 \
    } while (0)

#define WRITEST(R, BUF) do {                                                 \
        short8 xs0, xs1;                                                     \
        xs0[0] = f2bf(R.x0[0]); xs0[1] = f2bf(R.x0[1]);                      \
        xs0[2] = f2bf(R.x0[2]); xs0[3] = f2bf(R.x0[3]);                      \
        xs0[4] = f2bf(R.x1[0]); xs0[5] = f2bf(R.x1[1]);                      \
        xs0[6] = f2bf(R.x1[2]); xs0[7] = f2bf(R.x1[3]);                      \
        xs1[0] = f2bf(R.x2[0]); xs1[1] = f2bf(R.x2[1]);                      \
        xs1[2] = f2bf(R.x2[2]); xs1[3] = f2bf(R.x2[3]);                      \
        xs1[4] = f2bf(R.x3[0]); xs1[5] = f2bf(R.x3[1]);                      \
        xs1[6] = f2bf(R.x3[2]); xs1[7] = f2bf(R.x3[3]);                      \
        *(short8*)&Xlds[BUF][xr * 136 + xc * 16]     = xs0;                  \
        *(short8*)&Xlds[BUF][xr * 136 + xc * 16 + 8] = xs1;                  \
        short* lw = &Wlds[BUF][tid * 8];                                     \
        *(short8*)(lw)         = R.w0;                                       \
        *(short8*)(lw + 4096)  = R.w1;                                       \
        *(short8*)(lw + 8192)  = R.w2;                                       \
        *(short8*)(lw + 12288) = R.w3;                                       \
        *(short8*)(lw + 16384) = R.w4;                                       \
        *(short8*)(lw + 20480) = R.w5;                                       \
    } while (0)

#define COMPUTE(BUF) do {                                                    \
        const short* xb0 = &Xlds[BUF][(wr * 32 + lrow) * 136 + lgrp * 8];    \
        const short* xb1 = xb0 + 16 * 136;                                   \
        short8 a00 = *(const short8*)(xb0);                                  \
        short8 a01 = *(const short8*)(xb0 + 32);                             \
        short8 a02 = *(const short8*)(xb0 + 64);                             \
        short8 a03 = *(const short8*)(xb0 + 96);                             \
        short8 a10 = *(const short8*)(xb1);                                  \
        short8 a11 = *(const short8*)(xb1 + 32);                             \
        short8 a12 = *(const short8*)(xb1 + 64);                             \
        short8 a13 = *(const short8*)(xb1 + 96);                             \
        _Pragma("unroll")                                                    \
        for (int nf = 0; nf < 3; nf++) {                                     \
            int row = wc * 48 + nf * 16 + lrow;                              \
            int c0  = lgrp ^ (row & 7);                                      \
            const short* wb = &Wlds[BUF][row * 64];                          \
            short8 b0 = *(const short8*)(wb + c0 * 8);                       \
            short8 b1 = *(const short8*)(wb + (c0 ^ 4) * 8);                 \
            short8 b2 = *(const short8*)(wb + 12288 + c0 * 8);               \
            short8 b3 = *(const short8*)(wb + 12288 + (c0 ^ 4) * 8);         \
            acc0[nf] = __builtin_amdgcn_mfma_f32_16x16x32_bf16(a00, b0, acc0[nf], 0, 0, 0); \
            acc0[nf] = __builtin_amdgcn_mfma_f32_16x16x32_bf16(a01, b1, acc0[nf], 0, 0, 0); \
            acc0[nf] = __builtin_amdgcn_mfma_f32_16x16x32_bf16(a02, b2, acc0[nf], 0, 0, 0); \
            acc0[nf] = __builtin_amdgcn_mfma_f32_16x16x32_bf16(a03, b3, acc0[nf], 0, 0, 0); \
            acc1[nf] = __builtin_amdgcn_mfma_f32_16x16x32_bf16(a10, b0, acc1[nf], 0, 0, 0); \
            acc1[nf] = __builtin_amdgcn_mfma_f32_16x16x32_bf16(a11, b1, acc1[nf], 0, 0, 0); \
            acc1[nf] = __builtin_amdgcn_mfma_f32_16x16x32_bf16(a12, b2, acc1[nf], 0, 0, 0); \
            acc1[nf] = __builtin_amdgcn_mfma_f32_16x16x32_bf16(a13, b3, acc1[nf], 0, 0, 0); \
        }                                                                    \
    } while (0)

    LOADST(B, 0);
    WRITEST(B, 0);
    LOADST(A, 1);
    __syncthreads();

    for (int s = 0; s < 8; s += 2) {
        COMPUTE(0);
        WRITEST(A, 1);
        if (s + 2 < 8) LOADST(B, s + 2);
        __syncthreads();
        COMPUTE(1);
        if (s + 2 < 8) WRITEST(B, 0);
        if (s + 3 < 8) LOADST(A, s + 3);
        __syncthreads();
    }
#undef LOADST
#undef WRITEST
#undef COMPUTE

    {
#pragma unroll
        for (int nf = 0; nf < 3; nf++)
#pragma unroll
            for (int j = 0; j < 4; j++) {
                Wlds[0][(w * 2 + 0) * 896 + (lgrp * 4 + j) * 56 + nf * 16 + lrow] = f2bf(acc0[nf][j]);
                Wlds[0][(w * 2 + 1) * 896 + (lgrp * 4 + j) * 56 + nf * 16 + lrow] = f2bf(acc1[nf][j]);
            }
        __syncthreads();
#pragma unroll
        for (int k = 0; k < 3; k++) {
            int id   = tid + k * 512;
            int slab = id / 96;
            int rem  = id % 96;
            int rloc = rem / 6;
            int cm   = rem % 6;
            int w2  = slab >> 1;
            int rh  = slab & 1;
            int swr = w2 & 1;
            int swc = w2 >> 1;
            short8 v = *(const short8*)&Wlds[0][slab * 896 + rloc * 56 + cm * 8];
            int grow = rowbase + swr * 32 + rh * 16 + rloc;
            int gcol = swc * 48 + cm * 8;
            short* dst = (gcol < 64) ? qb : ((gcol < 128) ? kb : vb);
            *(short8*)(dst + (size_t)grow * H_ + (gcol & 63)) = v;
        }
    }
}

// ---------------------------------------------------------------------------
// Kernel 3: causal flash attention, QBLK=128 (8 waves x 16 q-rows),
// KVBLK=64, Klds staged, adaptive split <=8 KV-tiles/split.
// Grid = 8 batches x 40 split-units x 512 thr, big blocks first.
// qt in 0..15 (128-row tiles), T = 2*qt+2 KV-tiles, splits = ceil(T/8).
// g==0 (qt<=3, q<512): single split -> normalized f32 direct to out.
// Diagonal mask applies to the last TWO KV tiles (t >= T-2).
// ---------------------------------------------------------------------------
__global__ __launch_bounds__(512) void attn_kernel(
        const short* __restrict__ qb, const short* __restrict__ kb,
        const short* __restrict__ vb, short* __restrict__ Opart,
        float* __restrict__ ml, float* __restrict__ out) {
    __shared__ __align__(16) short Klds[2][4096];   // 2 x 8 KB
    __shared__ __align__(16) short Vt[64][72];      // V^T [h][kv], padded
    __shared__ __align__(16) short Ps[8][16][72];   // per-wave P (and O) tile

    int tid  = threadIdx.x;
    int lane = tid & 63;
    int w    = tid >> 6;               // 0..7
    int lrow = lane & 15;
    int lgrp = lane >> 4;
    int lk   = lgrp * 8;

    // ---- adaptive split mapping (reversed so big blocks launch first) ----
    int idx = 319 - (int)blockIdx.x;
    int b   = idx / 40;
    int r40 = idx - b * 40;
    int g, qt, sp;
    if      (r40 < 4)  { g = 0; qt = r40;                  sp = 0; }
    else if (r40 < 12) { g = 1; qt = 4 + ((r40 - 4) >> 1); sp = (r40 - 4) & 1; }
    else if (r40 < 24) { g = 2; qt = 8 + (r40 - 12) / 3;   sp = (r40 - 12) % 3; }
    else               { g = 3; qt = 12 + ((r40 - 24) >> 2); sp = (r40 - 24) & 3; }
    int q0 = qt * 128;
    int T  = 2 * qt + 2;               // KV tiles in causal range
    int t0 = sp * 8;
    int t1 = (T < t0 + 8) ? T : (t0 + 8);

    const short* kbase = kb + (size_t)b * S_ * H_;
    const short* vbase = vb + (size_t)b * S_ * H_;

    int qrow = q0 + w * 16 + lrow;
    const short* qptr = qb + ((size_t)b * S_ + qrow) * H_;
    short8 qf0 = *(const short8*)(qptr + lk);
    short8 qf1 = *(const short8*)(qptr + 32 + lk);

#define STAGE_K(TT, BUF) do {                                                 \
        int kv0s = (TT) * 64;                                                 \
        int rr = tid >> 3; int c = tid & 7;                                   \
        const short* pk = kbase + (size_t)(kv0s + rr) * H_ +                  \
                          ((c ^ (rr & 7)) << 3);                              \
        gl_lds16(pk, &Klds[BUF][tid * 8]);                                    \
    } while (0)

    // V staging map: thread -> (kv row, 8-h chunk)
    int kvr = tid >> 3;                // 0..63
    int hs  = (tid & 7) * 8;           // 0..56

    STAGE_K(t0, 0);
    const short* vp0 = vbase + (size_t)(t0 * 64 + kvr) * H_ + hs;
    short8 vr0 = *(const short8*)vp0;

    floatx4 O[4];
#pragma unroll
    for (int nf = 0; nf < 4; nf++) O[nf] = (floatx4){0.f, 0.f, 0.f, 0.f};
    float m[4], lsum[4];
#pragma unroll
    for (int j = 0; j < 4; j++) { m[j] = -1e30f; lsum[j] = 0.f; }

    for (int t = t0; t < t1; t++) {
        int cur = (t - t0) & 1;
        int kv0 = t * 64;
        __syncthreads();               // K(t) staged; Vt/Ps free

        if (t + 1 < t1) STAGE_K(t + 1, cur ^ 1);

        // write V(t) from regs (transposed)
#pragma unroll
        for (int c = 0; c < 8; c++) Vt[hs + c][kvr] = vr0[c];

        // prefetch V(t+1)
        if (t + 1 < t1) {
            const short* vp = vbase + (size_t)((t + 1) * 64 + kvr) * H_ + hs;
            vr0 = *(const short8*)vp;
        }

        // --- S = (Q K^T) * scale, K frags from swizzled LDS ---
        floatx4 s[4];
#pragma unroll
        for (int nf = 0; nf < 4; nf++) {
            int rr = nf * 16 + lrow;
            int c0 = lgrp ^ (rr & 7);
            const short* kp = &Klds[cur][rr * 64];
            short8 b0 = *(const short8*)(kp + c0 * 8);
            short8 b1 = *(const short8*)(kp + (c0 ^ 4) * 8);
            floatx4 a = (floatx4){0.f, 0.f, 0.f, 0.f};
            a = __builtin_amdgcn_mfma_f32_16x16x32_bf16(qf0, b0, a, 0, 0, 0);
            a = __builtin_amdgcn_mfma_f32_16x16x32_bf16(qf1, b1, a, 0, 0, 0);
            s[nf] = a;
        }
#pragma unroll
        for (int nf = 0; nf < 4; nf++)
#pragma unroll
            for (int j = 0; j < 4; j++) s[nf][j] *= 0.03125f;

        // --- causal mask: last two KV tiles intersect the diagonal ---
        if (t >= T - 2) {
#pragma unroll
            for (int nf = 0; nf < 4; nf++) {
                int kvidx = kv0 + nf * 16 + lrow;
#pragma unroll
                for (int j = 0; j < 4; j++) {
                    int qidx = q0 + w * 16 + lgrp * 4 + j;
                    if (kvidx > qidx) s[nf][j] = -1e30f;
                }
            }
        }

        // ---- phase-split online softmax ----
        float mx[4];
#pragma unroll
        for (int j = 0; j < 4; j++)
            mx[j] = fmaxf(fmaxf(s[0][j], s[1][j]), fmaxf(s[2][j], s[3][j]));
#pragma unroll
        for (int off = 1; off < 16; off <<= 1)
#pragma unroll
            for (int j = 0; j < 4; j++)
                mx[j] = fmaxf(mx[j], __shfl_xor(mx[j], off));

        float alpha[4], ps[4];
#pragma unroll
        for (int j = 0; j < 4; j++) {
            float mn = fmaxf(m[j], mx[j]);
            alpha[j] = exp2f((m[j] - mn) * LOG2E);
            m[j] = mn;
            float acc = 0.f;
#pragma unroll
            for (int nf = 0; nf < 4; nf++) {
                float p = exp2f((s[nf][j] - mn) * LOG2E);
                s[nf][j] = p;
                acc += p;
            }
            ps[j] = acc;
        }
#pragma unroll
        for (int off = 1; off < 16; off <<= 1)
#pragma unroll
            for (int j = 0; j < 4; j++)
                ps[j] += __shfl_xor(ps[j], off);
#pragma unroll
        for (int j = 0; j < 4; j++)
            lsum[j] = lsum[j] * alpha[j] + ps[j];

#pragma unroll
        for (int nf = 0; nf < 4; nf++) {
#pragma unroll
            for (int j = 0; j < 4; j++) {
                Ps[w][lgrp * 4 + j][nf * 16 + lrow] = f2bf(s[nf][j]);
                O[nf][j] *= alpha[j];
            }
        }
        __syncthreads();               // Ps + Vt visible

        short8 pa0 = *(const short8*)&Ps[w][lrow][lk];
        short8 pa1 = *(const short8*)&Ps[w][lrow][32 + lk];
#pragma unroll
        for (int nf = 0; nf < 4; nf++) {
            short8 vb0 = *(const short8*)&Vt[nf * 16 + lrow][lk];
            short8 vb1 = *(const short8*)&Vt[nf * 16 + lrow][32 + lk];
            O[nf] = __builtin_amdgcn_mfma_f32_16x16x32_bf16(pa0, vb0, O[nf], 0, 0, 0);
            O[nf] = __builtin_amdgcn_mfma_f32_16x16x32_bf16(pa1, vb1, O[nf], 0, 0, 0);
        }
    }
#undef STAGE_K

    if (g == 0) {
        // single split covers full causal range: normalized f32 direct out
#pragma unroll
        for (int nf = 0; nf < 4; nf++)
#pragma unroll
            for (int j = 0; j < 4; j++) {
                size_t grow = (size_t)b * S_ + q0 + w * 16 + lgrp * 4 + j;
                out[grow * H_ + nf * 16 + lrow] = O[nf][j] / lsum[j];
            }
        return;
    }

    // --- partial epilogue: m,l + transposed coalesced bf16 O stores ---
    size_t mlrow = (size_t)sp * 16384 + (size_t)b * S_ + q0 + w * 16 + lgrp * 4;
    if (lrow == 0) {
#pragma unroll
        for (int j = 0; j < 4; j++) {
            ml[(mlrow + j) * 2 + 0] = m[j];
            ml[(mlrow + j) * 2 + 1] = lsum[j];
        }
    }
    __syncthreads();                   // all PV reads of Ps done
#pragma unroll
    for (int nf = 0; nf < 4; nf++)
#pragma unroll
        for (int j = 0; j < 4; j++)
            Ps[w][lgrp * 4 + j][nf * 16 + lrow] = f2bf(O[nf][j]);
    __syncthreads();
    {
        int row = lane >> 2;
        int c   = lane & 3;
        short8 ov0 = *(const short8*)&Ps[w][row][c * 16];
        short8 ov1 = *(const short8*)&Ps[w][row][c * 16 + 8];
        size_t grow = (size_t)sp * 16384 + (size_t)b * S_ + q0 + w * 16 + row;
        *(short8*)(Opart + grow * H_ + c * 16) = ov0;
        *(short8*)(Opart + grow * H_ + c * 16 + 8) = ov1;
    }
}

// ---------------------------------------------------------------------------
// Kernel 4: combine partials for rows q >= 512.
// nact = ceil((2*(q>>7)+2)/8)  (QBLK=128 split geometry).
// ---------------------------------------------------------------------------
__global__ __launch_bounds__(256) void combine_kernel(
        const short* __restrict__ Opart, const float* __restrict__ ml,
        float* __restrict__ out) {
    int t = threadIdx.x;
    int rr = blockIdx.x * 4 + (t >> 6);    // 0..12287
    int h = t & 63;
    int b = rr / 1536;
    int q = 512 + (rr - b * 1536);
    size_t row = (size_t)b * S_ + q;
    int nact = (2 * (q >> 7) + 9) >> 3;    // ceil((2*qt+2)/8), 2..4

    float M = -1e30f;
    for (int s = 0; s < nact; s++)
        M = fmaxf(M, ml[((size_t)s * 16384 + row) * 2]);

    float L = 0.f, acc = 0.f;
    for (int s = 0; s < nact; s++) {
        float ms = ml[((size_t)s * 16384 + row) * 2];
        float ls = ml[((size_t)s * 16384 + row) * 2 + 1];
        float wgt = exp2f((ms - M) * LOG2E);
        L += wgt * ls;
        acc += wgt * bf2f(Opart[((size_t)s * 16384 + row) * H_ + h]);
    }
    out[row * H_ + h] = acc / L;
}

// ---------------------------------------------------------------------------
extern "C" void kernel_launch(void* const* d_in, const int* in_sizes, int n_in,
                              void* d_out, int out_size, void* d_ws, size_t ws_size,
                              hipStream_t stream) {
    const float* x  = (const float*)d_in[0];
    const float* wq = (const float*)d_in[1];
    const float* wk = (const float*)d_in[2];
    const float* wv = (const float*)d_in[3];
    float* out = (float*)d_out;

    char* ws = (char*)d_ws;
    const size_t WT_BYTES  = (size_t)192 * 1024 * 2;
    const size_t QKV_BYTES = (size_t)B_ * S_ * H_ * 2;
    const size_t ML_BYTES  = (size_t)4 * 16384 * 2 * 4;

    short* Wt = (short*)ws;
    short* qb = (short*)(ws + WT_BYTES);
    short* kb = (short*)(ws + WT_BYTES + QKV_BYTES);
    short* vb = (short*)(ws + WT_BYTES + 2 * QKV_BYTES);
    char*  mlp = ws + WT_BYTES + 3 * QKV_BYTES;
    char*  opp = mlp + ML_BYTES;

    wprep_kernel<<<48, 256, 0, stream>>>(wq, wk, wv, Wt);
    qkv_proj_kernel<<<256, 512, 0, stream>>>(x, Wt, qb, kb, vb);
    attn_kernel<<<320, 512, 0, stream>>>(qb, kb, vb,
            (short*)opp, (float*)mlp, out);
    combine_kernel<<<3072, 256, 0, stream>>>((const short*)opp,
            (const float*)mlp, out);
}

// Round 16
// 63.348 us; speedup vs baseline: 1.0943x; 1.0943x over previous
//
#include <hip/hip_runtime.h>
#include <hip/hip_bf16.h>

#define B_ 8
#define S_ 2048
#define E_ 1024
#define H_ 64
#define LOG2E 1.4426950408889634f

typedef __attribute__((ext_vector_type(8))) short short8;
typedef __attribute__((ext_vector_type(4))) float floatx4;
typedef unsigned int u32;

static __device__ __forceinline__ short f2bf(float f) {
    union { float f; unsigned u; } a; a.f = f;
    unsigned r = a.u + 0x7FFF + ((a.u >> 16) & 1);
    return (short)(r >> 16);
}
static __device__ __forceinline__ float bf2f(short s) {
    union { unsigned u; float f; } a; a.u = ((u32)(unsigned short)s) << 16;
    return a.f;
}
static __device__ __forceinline__ void gl_lds16(const void* g, void* l) {
    __builtin_amdgcn_global_load_lds(
        (const __attribute__((address_space(1))) u32*)(g),
        (__attribute__((address_space(3))) u32*)(l),
        16, 0, 0);
}

// ---------------------------------------------------------------------------
// Kernel 1: weights -> bf16, tiled per K-panel [16][192][64] with XOR chunk
// swizzle pre-applied in global.
// ---------------------------------------------------------------------------
__global__ __launch_bounds__(256) void wprep_kernel(
        const float* __restrict__ wq, const float* __restrict__ wk,
        const float* __restrict__ wv, short* __restrict__ Wt) {
    __shared__ short Ws[64][73];
    int bid = blockIdx.x;
    int m  = bid >> 4;
    int ec = bid & 15;
    const float* src = (m == 0) ? wq : ((m == 1) ? wk : wv);
    int t = threadIdx.x;
    {
        int er = t >> 2;
        int hc = (t & 3) * 16;
        const float* sp = src + (size_t)(ec * 64 + er) * H_ + hc;
        floatx4 v0 = *(const floatx4*)(sp);
        floatx4 v1 = *(const floatx4*)(sp + 4);
        floatx4 v2 = *(const floatx4*)(sp + 8);
        floatx4 v3 = *(const floatx4*)(sp + 12);
#pragma unroll
        for (int j = 0; j < 4; j++) Ws[er][hc + j]      = f2bf(v0[j]);
#pragma unroll
        for (int j = 0; j < 4; j++) Ws[er][hc + 4 + j]  = f2bf(v1[j]);
#pragma unroll
        for (int j = 0; j < 4; j++) Ws[er][hc + 8 + j]  = f2bf(v2[j]);
#pragma unroll
        for (int j = 0; j < 4; j++) Ws[er][hc + 12 + j] = f2bf(v3[j]);
    }
    __syncthreads();
    {
        int h  = t >> 2;
        int eo = (t & 3) * 16;
        int row = m * 64 + h;
        short* obase = Wt + (size_t)ec * 12288 + (size_t)row * 64;
#pragma unroll
        for (int g = 0; g < 2; g++) {
            short8 o;
#pragma unroll
            for (int jj = 0; jj < 8; jj++) o[jj] = Ws[eo + g * 8 + jj][h];
            int chunk = ((eo >> 3) + g) ^ (row & 7);
            *(short8*)(obase + chunk * 8) = o;
        }
    }
}

// ---------------------------------------------------------------------------
// Kernel 2: QKV projection GEMM (r10 version — best measured).
// BK=128, BM=64, grid 256, 512 thr = 8 waves (2 row x 4 col).
// ---------------------------------------------------------------------------
struct StageRegs {
    floatx4 x0, x1, x2, x3;
    short8 w0, w1, w2, w3, w4, w5;
};

__global__ __launch_bounds__(512, 2) void qkv_proj_kernel(
        const float* __restrict__ x, const short* __restrict__ Wt,
        short* __restrict__ qb, short* __restrict__ kb, short* __restrict__ vb) {
    __shared__ __align__(16) short Wlds[2][24576];
    __shared__ __align__(16) short Xlds[2][8704];

    int tid  = threadIdx.x;
    int lane = tid & 63;
    int w    = tid >> 6;
    int lrow = lane & 15;
    int lgrp = lane >> 4;

    int wr = w & 1;
    int wc = w >> 1;
    int rowbase = blockIdx.x * 64;

    int xr = tid >> 3;
    int xc = tid & 7;
    const float* xgp = x + (size_t)(rowbase + xr) * E_ + xc * 16;
    const short* wgp = Wt + (size_t)tid * 8;

    floatx4 acc0[3], acc1[3];
#pragma unroll
    for (int i = 0; i < 3; i++) {
        acc0[i] = (floatx4){0.f, 0.f, 0.f, 0.f};
        acc1[i] = (floatx4){0.f, 0.f, 0.f, 0.f};
    }

    StageRegs A, B;

#define LOADST(R, S) do {                                                    \
        const float* xn = xgp + (S) * 128;                                   \
        R.x0 = *(const floatx4*)(xn);                                        \
        R.x1 = *(const floatx4*)(xn + 4);                                    \
        R.x2 = *(const floatx4*)(xn + 8);                                    \
        R.x3 = *(const floatx4*)(xn + 12);                                   \
        const short* wn = wgp + (size_t)(S) * 24576;                         \
        R.w0 = *(const short8*)(wn);                                         \
        R.w1 = *(const short8*)(wn + 4096);                                  \
        R.w2 = *(const short8*)(wn + 8192);                                  \
        R.w3 = *(const short8*)(wn + 12288);                                 \
        R.w4 = *(const short8*)(wn + 16384);                                 \
        R.w5 = *(const short8*)(wn + 20480);                                 \
    } while (0)

#define WRITEST(R, BUF) do {                                                 \
        short8 xs0, xs1;                                                     \
        xs0[0] = f2bf(R.x0[0]); xs0[1] = f2bf(R.x0[1]);                      \
        xs0[2] = f2bf(R.x0[2]); xs0[3] = f2bf(R.x0[3]);                      \
        xs0[4] = f2bf(R.x1[0]); xs0[5] = f2bf(R.x1[1]);                      \
        xs0[6] = f2bf(R.x1[2]); xs0[7] = f2bf(R.x1[3]);                      \
        xs1[0] = f2bf(R.x2[0]); xs1[1] = f2bf(R.x2[1]);                      \
        xs1[2] = f2bf(R.x2[2]); xs1[3] = f2bf(R.x2[3]);                      \
        xs1[4] = f2bf(R.x3[0]); xs1[5] = f2bf(R.x3[1]);                      \
        xs1[6] = f2bf(R.x3[2]); xs1[7] = f2bf(R.x3[3]);                      \
        *(short8*)&Xlds[BUF][xr * 136 + xc * 16]     = xs0;                  \
        *(short8*)&Xlds[BUF][xr * 136 + xc * 16 + 8] = xs1;                  \
        short* lw = &Wlds[BUF][tid * 8];                                     \
        *(short8*)(lw)         = R.w0;                                       \
        *(short8*)(lw + 4096)  = R.w1;                                       \
        *(short8*)(lw + 8192)  = R.w2;                                       \
        *(short8*)(lw + 12288) = R.w3;                                       \
        *(short8*)(lw + 16384) = R.w4;                                       \
        *(short8*)(lw + 20480) = R.w5;                                       \
    } while (0)

#define COMPUTE(BUF) do {                                                    \
        const short* xb0 = &Xlds[BUF][(wr * 32 + lrow) * 136 + lgrp * 8];    \
        const short* xb1 = xb0 + 16 * 136;                                   \
        short8 a00 = *(const short8*)(xb0);                                  \
        short8 a01 = *(const short8*)(xb0 + 32);                             \
        short8 a02 = *(const short8*)(xb0 + 64);                             \
        short8 a03 = *(const short8*)(xb0 + 96);                             \
        short8 a10 = *(const short8*)(xb1);                                  \
        short8 a11 = *(const short8*)(xb1 + 32);                             \
        short8 a12 = *(const short8*)(xb1 + 64);                             \
        short8 a13 = *(const short8*)(xb1 + 96);                             \
        _Pragma("unroll")                                                    \
        for (int nf = 0; nf < 3; nf++) {                                     \
            int row = wc * 48 + nf * 16 + lrow;                              \
            int c0  = lgrp ^ (row & 7);                                      \
            const short* wb = &Wlds[BUF][row * 64];                          \
            short8 b0 = *(const short8*)(wb + c0 * 8);                       \
            short8 b1 = *(const short8*)(wb + (c0 ^ 4) * 8);                 \
            short8 b2 = *(const short8*)(wb + 12288 + c0 * 8);               \
            short8 b3 = *(const short8*)(wb + 12288 + (c0 ^ 4) * 8);         \
            acc0[nf] = __builtin_amdgcn_mfma_f32_16x16x32_bf16(a00, b0, acc0[nf], 0, 0, 0); \
            acc0[nf] = __builtin_amdgcn_mfma_f32_16x16x32_bf16(a01, b1, acc0[nf], 0, 0, 0); \
            acc0[nf] = __builtin_amdgcn_mfma_f32_16x16x32_bf16(a02, b2, acc0[nf], 0, 0, 0); \
            acc0[nf] = __builtin_amdgcn_mfma_f32_16x16x32_bf16(a03, b3, acc0[nf], 0, 0, 0); \
            acc1[nf] = __builtin_amdgcn_mfma_f32_16x16x32_bf16(a10, b0, acc1[nf], 0, 0, 0); \
            acc1[nf] = __builtin_amdgcn_mfma_f32_16x16x32_bf16(a11, b1, acc1[nf], 0, 0, 0); \
            acc1[nf] = __builtin_amdgcn_mfma_f32_16x16x32_bf16(a12, b2, acc1[nf], 0, 0, 0); \
            acc1[nf] = __builtin_amdgcn_mfma_f32_16x16x32_bf16(a13, b3, acc1[nf], 0, 0, 0); \
        }                                                                    \
    } while (0)

    LOADST(B, 0);
    WRITEST(B, 0);
    LOADST(A, 1);
    __syncthreads();

    for (int s = 0; s < 8; s += 2) {
        COMPUTE(0);
        WRITEST(A, 1);
        if (s + 2 < 8) LOADST(B, s + 2);
        __syncthreads();
        COMPUTE(1);
        if (s + 2 < 8) WRITEST(B, 0);
        if (s + 3 < 8) LOADST(A, s + 3);
        __syncthreads();
    }
#undef LOADST
#undef WRITEST
#undef COMPUTE

    {
#pragma unroll
        for (int nf = 0; nf < 3; nf++)
#pragma unroll
            for (int j = 0; j < 4; j++) {
                Wlds[0][(w * 2 + 0) * 896 + (lgrp * 4 + j) * 56 + nf * 16 + lrow] = f2bf(acc0[nf][j]);
                Wlds[0][(w * 2 + 1) * 896 + (lgrp * 4 + j) * 56 + nf * 16 + lrow] = f2bf(acc1[nf][j]);
            }
        __syncthreads();
#pragma unroll
        for (int k = 0; k < 3; k++) {
            int id   = tid + k * 512;
            int slab = id / 96;
            int rem  = id % 96;
            int rloc = rem / 6;
            int cm   = rem % 6;
            int w2  = slab >> 1;
            int rh  = slab & 1;
            int swr = w2 & 1;
            int swc = w2 >> 1;
            short8 v = *(const short8*)&Wlds[0][slab * 896 + rloc * 56 + cm * 8];
            int grow = rowbase + swr * 32 + rh * 16 + rloc;
            int gcol = swc * 48 + cm * 8;
            short* dst = (gcol < 64) ? qb : ((gcol < 128) ? kb : vb);
            *(short8*)(dst + (size_t)grow * H_ + (gcol & 63)) = v;
        }
    }
}

// ---------------------------------------------------------------------------
// Kernel 3: causal flash attention (r11 structure, KVBLK=64, Klds staged,
// 4 waves x 16 q-rows) with BALANCED adaptive split chunking: split sp of
// ns=g+1 covers base+(sp<rem) tiles (base=T/ns, rem=T%ns) — evens out the
// old 8+1 / 8+8+2 long poles.  Grid = 8 x 80 units, big blocks first.
// ---------------------------------------------------------------------------
__global__ __launch_bounds__(256) void attn_kernel(
        const short* __restrict__ qb, const short* __restrict__ kb,
        const short* __restrict__ vb, short* __restrict__ Opart,
        float* __restrict__ ml, float* __restrict__ out) {
    __shared__ __align__(16) short Klds[2][4096];
    __shared__ __align__(16) short Vt[64][72];
    __shared__ __align__(16) short Ps[4][16][72];

    int tid  = threadIdx.x;
    int lane = tid & 63;
    int w    = tid >> 6;
    int lrow = lane & 15;
    int lgrp = lane >> 4;
    int lk   = lgrp * 8;

    int idx = 639 - (int)blockIdx.x;
    int b   = idx / 80;
    int r80 = idx - b * 80;
    int g, base0;
    if      (r80 < 8)  { g = 0; base0 = 0;  }
    else if (r80 < 24) { g = 1; base0 = 8;  }
    else if (r80 < 48) { g = 2; base0 = 24; }
    else               { g = 3; base0 = 48; }
    int r    = r80 - base0;
    int gp1  = g + 1;
    int qloc = r / gp1;
    int sp   = r - qloc * gp1;
    int qt   = g * 8 + qloc;
    int q0   = qt * 64;
    int T    = qt + 1;
    // balanced chunking: sizes base or base+1, all splits non-empty
    int cbase = T / gp1;
    int crem  = T % gp1;
    int t0 = sp * cbase + ((sp < crem) ? sp : crem);
    int t1 = t0 + cbase + ((sp < crem) ? 1 : 0);

    const short* kbase = kb + (size_t)b * S_ * H_;
    const short* vbase = vb + (size_t)b * S_ * H_;

    int qrow = q0 + w * 16 + lrow;
    const short* qptr = qb + ((size_t)b * S_ + qrow) * H_;
    short8 qf0 = *(const short8*)(qptr + lk);
    short8 qf1 = *(const short8*)(qptr + 32 + lk);

#define STAGE_K(TT, BUF) do {                                                 \
        int kv0s = (TT) * 64;                                                 \
        _Pragma("unroll")                                                     \
        for (int it = 0; it < 2; it++) {                                      \
            int j = it * 256 + w * 64 + lane;                                 \
            int rr = j >> 3; int c = j & 7;                                   \
            const short* pk = kbase + (size_t)(kv0s + rr) * H_ +              \
                              ((c ^ (rr & 7)) << 3);                          \
            short* lkp = &Klds[BUF][(it * 256 + w * 64) * 8];                 \
            gl_lds16(pk, lkp);                                                \
        } } while (0)

    int kvr = tid >> 2;
    int hs  = (tid & 3) * 16;

    STAGE_K(t0, 0);
    const short* vp0 = vbase + (size_t)(t0 * 64 + kvr) * H_ + hs;
    short8 vr0 = *(const short8*)vp0;
    short8 vr1 = *(const short8*)(vp0 + 8);

    floatx4 O[4];
#pragma unroll
    for (int nf = 0; nf < 4; nf++) O[nf] = (floatx4){0.f, 0.f, 0.f, 0.f};
    float m[4], lsum[4];
#pragma unroll
    for (int j = 0; j < 4; j++) { m[j] = -1e30f; lsum[j] = 0.f; }

    for (int t = t0; t < t1; t++) {
        int cur = (t - t0) & 1;
        int kv0 = t * 64;
        __syncthreads();

        if (t + 1 < t1) STAGE_K(t + 1, cur ^ 1);

#pragma unroll
        for (int c = 0; c < 8; c++) Vt[hs + c][kvr] = vr0[c];
#pragma unroll
        for (int c = 0; c < 8; c++) Vt[hs + 8 + c][kvr] = vr1[c];

        if (t + 1 < t1) {
            const short* vp = vbase + (size_t)((t + 1) * 64 + kvr) * H_ + hs;
            vr0 = *(const short8*)vp;
            vr1 = *(const short8*)(vp + 8);
        }

        floatx4 s[4];
#pragma unroll
        for (int nf = 0; nf < 4; nf++) {
            int rr = nf * 16 + lrow;
            int c0 = lgrp ^ (rr & 7);
            const short* kp = &Klds[cur][rr * 64];
            short8 b0 = *(const short8*)(kp + c0 * 8);
            short8 b1 = *(const short8*)(kp + (c0 ^ 4) * 8);
            floatx4 a = (floatx4){0.f, 0.f, 0.f, 0.f};
            a = __builtin_amdgcn_mfma_f32_16x16x32_bf16(qf0, b0, a, 0, 0, 0);
            a = __builtin_amdgcn_mfma_f32_16x16x32_bf16(qf1, b1, a, 0, 0, 0);
            s[nf] = a;
        }
#pragma unroll
        for (int nf = 0; nf < 4; nf++)
#pragma unroll
            for (int j = 0; j < 4; j++) s[nf][j] *= 0.03125f;

        if (t == qt) {
#pragma unroll
            for (int nf = 0; nf < 4; nf++) {
                int kvidx = kv0 + nf * 16 + lrow;
#pragma unroll
                for (int j = 0; j < 4; j++) {
                    int qidx = q0 + w * 16 + lgrp * 4 + j;
                    if (kvidx > qidx) s[nf][j] = -1e30f;
                }
            }
        }

        float alpha[4];
#pragma unroll
        for (int j = 0; j < 4; j++) {
            float mx = fmaxf(fmaxf(s[0][j], s[1][j]), fmaxf(s[2][j], s[3][j]));
#pragma unroll
            for (int off = 1; off < 16; off <<= 1)
                mx = fmaxf(mx, __shfl_xor(mx, off));
            float mn = fmaxf(m[j], mx);
            alpha[j] = exp2f((m[j] - mn) * LOG2E);
            m[j] = mn;
            float ps = 0.f;
#pragma unroll
            for (int nf = 0; nf < 4; nf++) {
                float p = exp2f((s[nf][j] - mn) * LOG2E);
                s[nf][j] = p;
                ps += p;
            }
#pragma unroll
            for (int off = 1; off < 16; off <<= 1)
                ps += __shfl_xor(ps, off);
            lsum[j] = lsum[j] * alpha[j] + ps;
        }

#pragma unroll
        for (int nf = 0; nf < 4; nf++) {
#pragma unroll
            for (int j = 0; j < 4; j++) {
                Ps[w][lgrp * 4 + j][nf * 16 + lrow] = f2bf(s[nf][j]);
                O[nf][j] *= alpha[j];
            }
        }
        __syncthreads();

        short8 pa0 = *(const short8*)&Ps[w][lrow][lk];
        short8 pa1 = *(const short8*)&Ps[w][lrow][32 + lk];
#pragma unroll
        for (int nf = 0; nf < 4; nf++) {
            short8 vb0 = *(const short8*)&Vt[nf * 16 + lrow][lk];
            short8 vb1 = *(const short8*)&Vt[nf * 16 + lrow][32 + lk];
            O[nf] = __builtin_amdgcn_mfma_f32_16x16x32_bf16(pa0, vb0, O[nf], 0, 0, 0);
            O[nf] = __builtin_amdgcn_mfma_f32_16x16x32_bf16(pa1, vb1, O[nf], 0, 0, 0);
        }
    }
#undef STAGE_K

    if (g == 0) {
#pragma unroll
        for (int nf = 0; nf < 4; nf++)
#pragma unroll
            for (int j = 0; j < 4; j++) {
                size_t grow = (size_t)b * S_ + q0 + w * 16 + lgrp * 4 + j;
                out[grow * H_ + nf * 16 + lrow] = O[nf][j] / lsum[j];
            }
        return;
    }

    size_t mlrow = (size_t)sp * 16384 + (size_t)b * S_ + q0 + w * 16 + lgrp * 4;
    if (lrow == 0) {
#pragma unroll
        for (int j = 0; j < 4; j++) {
            ml[(mlrow + j) * 2 + 0] = m[j];
            ml[(mlrow + j) * 2 + 1] = lsum[j];
        }
    }
    __syncthreads();
#pragma unroll
    for (int nf = 0; nf < 4; nf++)
#pragma unroll
        for (int j = 0; j < 4; j++)
            Ps[w][lgrp * 4 + j][nf * 16 + lrow] = f2bf(O[nf][j]);
    __syncthreads();
    {
        int row = lane >> 2;
        int c   = lane & 3;
        short8 ov0 = *(const short8*)&Ps[w][row][c * 16];
        short8 ov1 = *(const short8*)&Ps[w][row][c * 16 + 8];
        size_t grow = (size_t)sp * 16384 + (size_t)b * S_ + q0 + w * 16 + row;
        *(short8*)(Opart + grow * H_ + c * 16) = ov0;
        *(short8*)(Opart + grow * H_ + c * 16 + 8) = ov1;
    }
}

// ---------------------------------------------------------------------------
// Kernel 4: combine partials for rows q >= 512 (unchanged; nact = g+1 splits,
// all non-empty under balanced chunking).
// ---------------------------------------------------------------------------
__global__ __launch_bounds__(256) void combine_kernel(
        const short* __restrict__ Opart, const float* __restrict__ ml,
        float* __restrict__ out) {
    int t = threadIdx.x;
    int rr = blockIdx.x * 4 + (t >> 6);
    int h = t & 63;
    int b = rr / 1536;
    int q = 512 + (rr - b * 1536);
    size_t row = (size_t)b * S_ + q;
    int nact = ((q >> 6) >> 3) + 1;

    float M = -1e30f;
    for (int s = 0; s < nact; s++)
        M = fmaxf(M, ml[((size_t)s * 16384 + row) * 2]);

    float L = 0.f, acc = 0.f;
    for (int s = 0; s < nact; s++) {
        float ms = ml[((size_t)s * 16384 + row) * 2];
        float ls = ml[((size_t)s * 16384 + row) * 2 + 1];
        float wgt = exp2f((ms - M) * LOG2E);
        L += wgt * ls;
        acc += wgt * bf2f(Opart[((size_t)s * 16384 + row) * H_ + h]);
    }
    out[row * H_ + h] = acc / L;
}

// ---------------------------------------------------------------------------
extern "C" void kernel_launch(void* const* d_in, const int* in_sizes, int n_in,
                              void* d_out, int out_size, void* d_ws, size_t ws_size,
                              hipStream_t stream) {
    const float* x  = (const float*)d_in[0];
    const float* wq = (const float*)d_in[1];
    const float* wk = (const float*)d_in[2];
    const float* wv = (const float*)d_in[3];
    float* out = (float*)d_out;

    char* ws = (char*)d_ws;
    const size_t WT_BYTES  = (size_t)192 * 1024 * 2;
    const size_t QKV_BYTES = (size_t)B_ * S_ * H_ * 2;
    const size_t ML_BYTES  = (size_t)4 * 16384 * 2 * 4;

    short* Wt = (short*)ws;
    short* qb = (short*)(ws + WT_BYTES);
    short* kb = (short*)(ws + WT_BYTES + QKV_BYTES);
    short* vb = (short*)(ws + WT_BYTES + 2 * QKV_BYTES);
    char*  mlp = ws + WT_BYTES + 3 * QKV_BYTES;
    char*  opp = mlp + ML_BYTES;

    wprep_kernel<<<48, 256, 0, stream>>>(wq, wk, wv, Wt);
    qkv_proj_kernel<<<256, 512, 0, stream>>>(x, Wt, qb, kb, vb);
    attn_kernel<<<640, 256, 0, stream>>>(qb, kb, vb,
            (short*)opp, (float*)mlp, out);
    combine_kernel<<<3072, 256, 0, stream>>>((const short*)opp,
            (const float*)mlp, out);
}

// Round 17
// 60.550 us; speedup vs baseline: 1.1448x; 1.0462x over previous
//
#include <hip/hip_runtime.h>
#include <hip/hip_bf16.h>

#define B_ 8
#define S_ 2048
#define E_ 1024
#define H_ 64
#define LOG2E 1.4426950408889634f

typedef __attribute__((ext_vector_type(8))) short short8;
typedef __attribute__((ext_vector_type(4))) float floatx4;
typedef unsigned int u32;

static __device__ __forceinline__ short f2bf(float f) {
    union { float f; unsigned u; } a; a.f = f;
    unsigned r = a.u + 0x7FFF + ((a.u >> 16) & 1);
    return (short)(r >> 16);
}
static __device__ __forceinline__ float bf2f(short s) {
    union { unsigned u; float f; } a; a.u = ((u32)(unsigned short)s) << 16;
    return a.f;
}
static __device__ __forceinline__ void gl_lds16(const void* g, void* l) {
    __builtin_amdgcn_global_load_lds(
        (const __attribute__((address_space(1))) u32*)(g),
        (__attribute__((address_space(3))) u32*)(l),
        16, 0, 0);
}

// ---------------------------------------------------------------------------
// Kernel 1: weights -> bf16, tiled per K-panel [16][192][64] with XOR chunk
// swizzle pre-applied in global.
// ---------------------------------------------------------------------------
__global__ __launch_bounds__(256) void wprep_kernel(
        const float* __restrict__ wq, const float* __restrict__ wk,
        const float* __restrict__ wv, short* __restrict__ Wt) {
    __shared__ short Ws[64][73];
    int bid = blockIdx.x;
    int m  = bid >> 4;
    int ec = bid & 15;
    const float* src = (m == 0) ? wq : ((m == 1) ? wk : wv);
    int t = threadIdx.x;
    {
        int er = t >> 2;
        int hc = (t & 3) * 16;
        const float* sp = src + (size_t)(ec * 64 + er) * H_ + hc;
        floatx4 v0 = *(const floatx4*)(sp);
        floatx4 v1 = *(const floatx4*)(sp + 4);
        floatx4 v2 = *(const floatx4*)(sp + 8);
        floatx4 v3 = *(const floatx4*)(sp + 12);
#pragma unroll
        for (int j = 0; j < 4; j++) Ws[er][hc + j]      = f2bf(v0[j]);
#pragma unroll
        for (int j = 0; j < 4; j++) Ws[er][hc + 4 + j]  = f2bf(v1[j]);
#pragma unroll
        for (int j = 0; j < 4; j++) Ws[er][hc + 8 + j]  = f2bf(v2[j]);
#pragma unroll
        for (int j = 0; j < 4; j++) Ws[er][hc + 12 + j] = f2bf(v3[j]);
    }
    __syncthreads();
    {
        int h  = t >> 2;
        int eo = (t & 3) * 16;
        int row = m * 64 + h;
        short* obase = Wt + (size_t)ec * 12288 + (size_t)row * 64;
#pragma unroll
        for (int g = 0; g < 2; g++) {
            short8 o;
#pragma unroll
            for (int jj = 0; jj < 8; jj++) o[jj] = Ws[eo + g * 8 + jj][h];
            int chunk = ((eo >> 3) + g) ^ (row & 7);
            *(short8*)(obase + chunk * 8) = o;
        }
    }
}

// ---------------------------------------------------------------------------
// Kernel 2: QKV projection GEMM (r10 version — best measured).
// BK=128, BM=64, grid 256, 512 thr = 8 waves (2 row x 4 col).
// ---------------------------------------------------------------------------
struct StageRegs {
    floatx4 x0, x1, x2, x3;
    short8 w0, w1, w2, w3, w4, w5;
};

__global__ __launch_bounds__(512, 2) void qkv_proj_kernel(
        const float* __restrict__ x, const short* __restrict__ Wt,
        short* __restrict__ qb, short* __restrict__ kb, short* __restrict__ vb) {
    __shared__ __align__(16) short Wlds[2][24576];
    __shared__ __align__(16) short Xlds[2][8704];

    int tid  = threadIdx.x;
    int lane = tid & 63;
    int w    = tid >> 6;
    int lrow = lane & 15;
    int lgrp = lane >> 4;

    int wr = w & 1;
    int wc = w >> 1;
    int rowbase = blockIdx.x * 64;

    int xr = tid >> 3;
    int xc = tid & 7;
    const float* xgp = x + (size_t)(rowbase + xr) * E_ + xc * 16;
    const short* wgp = Wt + (size_t)tid * 8;

    floatx4 acc0[3], acc1[3];
#pragma unroll
    for (int i = 0; i < 3; i++) {
        acc0[i] = (floatx4){0.f, 0.f, 0.f, 0.f};
        acc1[i] = (floatx4){0.f, 0.f, 0.f, 0.f};
    }

    StageRegs A, B;

#define LOADST(R, S) do {                                                    \
        const float* xn = xgp + (S) * 128;                                   \
        R.x0 = *(const floatx4*)(xn);                                        \
        R.x1 = *(const floatx4*)(xn + 4);                                    \
        R.x2 = *(const floatx4*)(xn + 8);                                    \
        R.x3 = *(const floatx4*)(xn + 12);                                   \
        const short* wn = wgp + (size_t)(S) * 24576;                         \
        R.w0 = *(const short8*)(wn);                                         \
        R.w1 = *(const short8*)(wn + 4096);                                  \
        R.w2 = *(const short8*)(wn + 8192);                                  \
        R.w3 = *(const short8*)(wn + 12288);                                 \
        R.w4 = *(const short8*)(wn + 16384);                                 \
        R.w5 = *(const short8*)(wn + 20480);                                 \
    } while (0)

#define WRITEST(R, BUF) do {                                                 \
        short8 xs0, xs1;                                                     \
        xs0[0] = f2bf(R.x0[0]); xs0[1] = f2bf(R.x0[1]);                      \
        xs0[2] = f2bf(R.x0[2]); xs0[3] = f2bf(R.x0[3]);                      \
        xs0[4] = f2bf(R.x1[0]); xs0[5] = f2bf(R.x1[1]);                      \
        xs0[6] = f2bf(R.x1[2]); xs0[7] = f2bf(R.x1[3]);                      \
        xs1[0] = f2bf(R.x2[0]); xs1[1] = f2bf(R.x2[1]);                      \
        xs1[2] = f2bf(R.x2[2]); xs1[3] = f2bf(R.x2[3]);                      \
        xs1[4] = f2bf(R.x3[0]); xs1[5] = f2bf(R.x3[1]);                      \
        xs1[6] = f2bf(R.x3[2]); xs1[7] = f2bf(R.x3[3]);                      \
        *(short8*)&Xlds[BUF][xr * 136 + xc * 16]     = xs0;                  \
        *(short8*)&Xlds[BUF][xr * 136 + xc * 16 + 8] = xs1;                  \
        short* lw = &Wlds[BUF][tid * 8];                                     \
        *(short8*)(lw)         = R.w0;                                       \
        *(short8*)(lw + 4096)  = R.w1;                                       \
        *(short8*)(lw + 8192)  = R.w2;                                       \
        *(short8*)(lw + 12288) = R.w3;                                       \
        *(short8*)(lw + 16384) = R.w4;                                       \
        *(short8*)(lw + 20480) = R.w5;                                       \
    } while (0)

#define COMPUTE(BUF) do {                                                    \
        const short* xb0 = &Xlds[BUF][(wr * 32 + lrow) * 136 + lgrp * 8];    \
        const short* xb1 = xb0 + 16 * 136;                                   \
        short8 a00 = *(const short8*)(xb0);                                  \
        short8 a01 = *(const short8*)(xb0 + 32);                             \
        short8 a02 = *(const short8*)(xb0 + 64);                             \
        short8 a03 = *(const short8*)(xb0 + 96);                             \
        short8 a10 = *(const short8*)(xb1);                                  \
        short8 a11 = *(const short8*)(xb1 + 32);                             \
        short8 a12 = *(const short8*)(xb1 + 64);                             \
        short8 a13 = *(const short8*)(xb1 + 96);                             \
        _Pragma("unroll")                                                    \
        for (int nf = 0; nf < 3; nf++) {                                     \
            int row = wc * 48 + nf * 16 + lrow;                              \
            int c0  = lgrp ^ (row & 7);                                      \
            const short* wb = &Wlds[BUF][row * 64];                          \
            short8 b0 = *(const short8*)(wb + c0 * 8);                       \
            short8 b1 = *(const short8*)(wb + (c0 ^ 4) * 8);                 \
            short8 b2 = *(const short8*)(wb + 12288 + c0 * 8);               \
            short8 b3 = *(const short8*)(wb + 12288 + (c0 ^ 4) * 8);         \
            acc0[nf] = __builtin_amdgcn_mfma_f32_16x16x32_bf16(a00, b0, acc0[nf], 0, 0, 0); \
            acc0[nf] = __builtin_amdgcn_mfma_f32_16x16x32_bf16(a01, b1, acc0[nf], 0, 0, 0); \
            acc0[nf] = __builtin_amdgcn_mfma_f32_16x16x32_bf16(a02, b2, acc0[nf], 0, 0, 0); \
            acc0[nf] = __builtin_amdgcn_mfma_f32_16x16x32_bf16(a03, b3, acc0[nf], 0, 0, 0); \
            acc1[nf] = __builtin_amdgcn_mfma_f32_16x16x32_bf16(a10, b0, acc1[nf], 0, 0, 0); \
            acc1[nf] = __builtin_amdgcn_mfma_f32_16x16x32_bf16(a11, b1, acc1[nf], 0, 0, 0); \
            acc1[nf] = __builtin_amdgcn_mfma_f32_16x16x32_bf16(a12, b2, acc1[nf], 0, 0, 0); \
            acc1[nf] = __builtin_amdgcn_mfma_f32_16x16x32_bf16(a13, b3, acc1[nf], 0, 0, 0); \
        }                                                                    \
    } while (0)

    LOADST(B, 0);
    WRITEST(B, 0);
    LOADST(A, 1);
    __syncthreads();

    for (int s = 0; s < 8; s += 2) {
        COMPUTE(0);
        WRITEST(A, 1);
        if (s + 2 < 8) LOADST(B, s + 2);
        __syncthreads();
        COMPUTE(1);
        if (s + 2 < 8) WRITEST(B, 0);
        if (s + 3 < 8) LOADST(A, s + 3);
        __syncthreads();
    }
#undef LOADST
#undef WRITEST
#undef COMPUTE

    {
#pragma unroll
        for (int nf = 0; nf < 3; nf++)
#pragma unroll
            for (int j = 0; j < 4; j++) {
                Wlds[0][(w * 2 + 0) * 896 + (lgrp * 4 + j) * 56 + nf * 16 + lrow] = f2bf(acc0[nf][j]);
                Wlds[0][(w * 2 + 1) * 896 + (lgrp * 4 + j) * 56 + nf * 16 + lrow] = f2bf(acc1[nf][j]);
            }
        __syncthreads();
#pragma unroll
        for (int k = 0; k < 3; k++) {
            int id   = tid + k * 512;
            int slab = id / 96;
            int rem  = id % 96;
            int rloc = rem / 6;
            int cm   = rem % 6;
            int w2  = slab >> 1;
            int rh  = slab & 1;
            int swr = w2 & 1;
            int swc = w2 >> 1;
            short8 v = *(const short8*)&Wlds[0][slab * 896 + rloc * 56 + cm * 8];
            int grow = rowbase + swr * 32 + rh * 16 + rloc;
            int gcol = swc * 48 + cm * 8;
            short* dst = (gcol < 64) ? qb : ((gcol < 128) ? kb : vb);
            *(short8*)(dst + (size_t)grow * H_ + (gcol & 63)) = v;
        }
    }
}

// ---------------------------------------------------------------------------
// Kernel 3: causal flash attention (r11 structure, KVBLK=64, Klds staged,
// 4 waves x 16 q-rows) with balanced adaptive split chunking.
// ---------------------------------------------------------------------------
__global__ __launch_bounds__(256) void attn_kernel(
        const short* __restrict__ qb, const short* __restrict__ kb,
        const short* __restrict__ vb, short* __restrict__ Opart,
        float* __restrict__ ml, float* __restrict__ out) {
    __shared__ __align__(16) short Klds[2][4096];
    __shared__ __align__(16) short Vt[64][72];
    __shared__ __align__(16) short Ps[4][16][72];

    int tid  = threadIdx.x;
    int lane = tid & 63;
    int w    = tid >> 6;
    int lrow = lane & 15;
    int lgrp = lane >> 4;
    int lk   = lgrp * 8;

    int idx = 639 - (int)blockIdx.x;
    int b   = idx / 80;
    int r80 = idx - b * 80;
    int g, base0;
    if      (r80 < 8)  { g = 0; base0 = 0;  }
    else if (r80 < 24) { g = 1; base0 = 8;  }
    else if (r80 < 48) { g = 2; base0 = 24; }
    else               { g = 3; base0 = 48; }
    int r    = r80 - base0;
    int gp1  = g + 1;
    int qloc = r / gp1;
    int sp   = r - qloc * gp1;
    int qt   = g * 8 + qloc;
    int q0   = qt * 64;
    int T    = qt + 1;
    int cbase = T / gp1;
    int crem  = T % gp1;
    int t0 = sp * cbase + ((sp < crem) ? sp : crem);
    int t1 = t0 + cbase + ((sp < crem) ? 1 : 0);

    const short* kbase = kb + (size_t)b * S_ * H_;
    const short* vbase = vb + (size_t)b * S_ * H_;

    int qrow = q0 + w * 16 + lrow;
    const short* qptr = qb + ((size_t)b * S_ + qrow) * H_;
    short8 qf0 = *(const short8*)(qptr + lk);
    short8 qf1 = *(const short8*)(qptr + 32 + lk);

#define STAGE_K(TT, BUF) do {                                                 \
        int kv0s = (TT) * 64;                                                 \
        _Pragma("unroll")                                                     \
        for (int it = 0; it < 2; it++) {                                      \
            int j = it * 256 + w * 64 + lane;                                 \
            int rr = j >> 3; int c = j & 7;                                   \
            const short* pk = kbase + (size_t)(kv0s + rr) * H_ +              \
                              ((c ^ (rr & 7)) << 3);                          \
            short* lkp = &Klds[BUF][(it * 256 + w * 64) * 8];                 \
            gl_lds16(pk, lkp);                                                \
        } } while (0)

    int kvr = tid >> 2;
    int hs  = (tid & 3) * 16;

    STAGE_K(t0, 0);
    const short* vp0 = vbase + (size_t)(t0 * 64 + kvr) * H_ + hs;
    short8 vr0 = *(const short8*)vp0;
    short8 vr1 = *(const short8*)(vp0 + 8);

    floatx4 O[4];
#pragma unroll
    for (int nf = 0; nf < 4; nf++) O[nf] = (floatx4){0.f, 0.f, 0.f, 0.f};
    float m[4], lsum[4];
#pragma unroll
    for (int j = 0; j < 4; j++) { m[j] = -1e30f; lsum[j] = 0.f; }

    for (int t = t0; t < t1; t++) {
        int cur = (t - t0) & 1;
        int kv0 = t * 64;
        __syncthreads();

        if (t + 1 < t1) STAGE_K(t + 1, cur ^ 1);

#pragma unroll
        for (int c = 0; c < 8; c++) Vt[hs + c][kvr] = vr0[c];
#pragma unroll
        for (int c = 0; c < 8; c++) Vt[hs + 8 + c][kvr] = vr1[c];

        if (t + 1 < t1) {
            const short* vp = vbase + (size_t)((t + 1) * 64 + kvr) * H_ + hs;
            vr0 = *(const short8*)vp;
            vr1 = *(const short8*)(vp + 8);
        }

        floatx4 s[4];
#pragma unroll
        for (int nf = 0; nf < 4; nf++) {
            int rr = nf * 16 + lrow;
            int c0 = lgrp ^ (rr & 7);
            const short* kp = &Klds[cur][rr * 64];
            short8 b0 = *(const short8*)(kp + c0 * 8);
            short8 b1 = *(const short8*)(kp + (c0 ^ 4) * 8);
            floatx4 a = (floatx4){0.f, 0.f, 0.f, 0.f};
            a = __builtin_amdgcn_mfma_f32_16x16x32_bf16(qf0, b0, a, 0, 0, 0);
            a = __builtin_amdgcn_mfma_f32_16x16x32_bf16(qf1, b1, a, 0, 0, 0);
            s[nf] = a;
        }
#pragma unroll
        for (int nf = 0; nf < 4; nf++)
#pragma unroll
            for (int j = 0; j < 4; j++) s[nf][j] *= 0.03125f;

        if (t == qt) {
#pragma unroll
            for (int nf = 0; nf < 4; nf++) {
                int kvidx = kv0 + nf * 16 + lrow;
#pragma unroll
                for (int j = 0; j < 4; j++) {
                    int qidx = q0 + w * 16 + lgrp * 4 + j;
                    if (kvidx > qidx) s[nf][j] = -1e30f;
                }
            }
        }

        float alpha[4];
#pragma unroll
        for (int j = 0; j < 4; j++) {
            float mx = fmaxf(fmaxf(s[0][j], s[1][j]), fmaxf(s[2][j], s[3][j]));
#pragma unroll
            for (int off = 1; off < 16; off <<= 1)
                mx = fmaxf(mx, __shfl_xor(mx, off));
            float mn = fmaxf(m[j], mx);
            alpha[j] = exp2f((m[j] - mn) * LOG2E);
            m[j] = mn;
            float ps = 0.f;
#pragma unroll
            for (int nf = 0; nf < 4; nf++) {
                float p = exp2f((s[nf][j] - mn) * LOG2E);
                s[nf][j] = p;
                ps += p;
            }
#pragma unroll
            for (int off = 1; off < 16; off <<= 1)
                ps += __shfl_xor(ps, off);
            lsum[j] = lsum[j] * alpha[j] + ps;
        }

#pragma unroll
        for (int nf = 0; nf < 4; nf++) {
#pragma unroll
            for (int j = 0; j < 4; j++) {
                Ps[w][lgrp * 4 + j][nf * 16 + lrow] = f2bf(s[nf][j]);
                O[nf][j] *= alpha[j];
            }
        }
        __syncthreads();

        short8 pa0 = *(const short8*)&Ps[w][lrow][lk];
        short8 pa1 = *(const short8*)&Ps[w][lrow][32 + lk];
#pragma unroll
        for (int nf = 0; nf < 4; nf++) {
            short8 vb0 = *(const short8*)&Vt[nf * 16 + lrow][lk];
            short8 vb1 = *(const short8*)&Vt[nf * 16 + lrow][32 + lk];
            O[nf] = __builtin_amdgcn_mfma_f32_16x16x32_bf16(pa0, vb0, O[nf], 0, 0, 0);
            O[nf] = __builtin_amdgcn_mfma_f32_16x16x32_bf16(pa1, vb1, O[nf], 0, 0, 0);
        }
    }
#undef STAGE_K

    if (g == 0) {
#pragma unroll
        for (int nf = 0; nf < 4; nf++)
#pragma unroll
            for (int j = 0; j < 4; j++) {
                size_t grow = (size_t)b * S_ + q0 + w * 16 + lgrp * 4 + j;
                out[grow * H_ + nf * 16 + lrow] = O[nf][j] / lsum[j];
            }
        return;
    }

    size_t mlrow = (size_t)sp * 16384 + (size_t)b * S_ + q0 + w * 16 + lgrp * 4;
    if (lrow == 0) {
#pragma unroll
        for (int j = 0; j < 4; j++) {
            ml[(mlrow + j) * 2 + 0] = m[j];
            ml[(mlrow + j) * 2 + 1] = lsum[j];
        }
    }
    __syncthreads();
#pragma unroll
    for (int nf = 0; nf < 4; nf++)
#pragma unroll
        for (int j = 0; j < 4; j++)
            Ps[w][lgrp * 4 + j][nf * 16 + lrow] = f2bf(O[nf][j]);
    __syncthreads();
    {
        int row = lane >> 2;
        int c   = lane & 3;
        short8 ov0 = *(const short8*)&Ps[w][row][c * 16];
        short8 ov1 = *(const short8*)&Ps[w][row][c * 16 + 8];
        size_t grow = (size_t)sp * 16384 + (size_t)b * S_ + q0 + w * 16 + row;
        *(short8*)(Opart + grow * H_ + c * 16) = ov0;
        *(short8*)(Opart + grow * H_ + c * 16 + 8) = ov1;
    }
}

// ---------------------------------------------------------------------------
// Kernel 4: combine partials for rows q >= 512 — VECTORIZED (G13).
// 8 threads per row, each owns 8 h: short8 partial loads, floatx4 x2 stores.
// Grid = 12288 rows / 32 rows-per-block = 384 blocks.
// ---------------------------------------------------------------------------
__global__ __launch_bounds__(256) void combine_kernel(
        const short* __restrict__ Opart, const float* __restrict__ ml,
        float* __restrict__ out) {
    int t = threadIdx.x;
    int rr = blockIdx.x * 32 + (t >> 3);   // 0..12287
    int hc = (t & 7) * 8;
    int b = rr / 1536;
    int q = 512 + (rr - b * 1536);
    size_t row = (size_t)b * S_ + q;
    int nact = ((q >> 6) >> 3) + 1;        // 2..4

    float M = -1e30f;
    for (int s = 0; s < nact; s++)
        M = fmaxf(M, ml[((size_t)s * 16384 + row) * 2]);

    float L = 0.f;
    float acc[8];
#pragma unroll
    for (int i = 0; i < 8; i++) acc[i] = 0.f;
    for (int s = 0; s < nact; s++) {
        float ms = ml[((size_t)s * 16384 + row) * 2];
        float ls = ml[((size_t)s * 16384 + row) * 2 + 1];
        float wgt = exp2f((ms - M) * LOG2E);
        L += wgt * ls;
        short8 ov = *(const short8*)(Opart + ((size_t)s * 16384 + row) * H_ + hc);
#pragma unroll
        for (int i = 0; i < 8; i++) acc[i] += wgt * bf2f(ov[i]);
    }
    float invL = 1.f / L;
    floatx4 o0, o1;
#pragma unroll
    for (int i = 0; i < 4; i++) { o0[i] = acc[i] * invL; o1[i] = acc[4 + i] * invL; }
    float* op = out + row * H_ + hc;
    *(floatx4*)op = o0;
    *(floatx4*)(op + 4) = o1;
}

// ---------------------------------------------------------------------------
extern "C" void kernel_launch(void* const* d_in, const int* in_sizes, int n_in,
                              void* d_out, int out_size, void* d_ws, size_t ws_size,
                              hipStream_t stream) {
    const float* x  = (const float*)d_in[0];
    const float* wq = (const float*)d_in[1];
    const float* wk = (const float*)d_in[2];
    const float* wv = (const float*)d_in[3];
    float* out = (float*)d_out;

    char* ws = (char*)d_ws;
    const size_t WT_BYTES  = (size_t)192 * 1024 * 2;
    const size_t QKV_BYTES = (size_t)B_ * S_ * H_ * 2;
    const size_t ML_BYTES  = (size_t)4 * 16384 * 2 * 4;

    short* Wt = (short*)ws;
    short* qb = (short*)(ws + WT_BYTES);
    short* kb = (short*)(ws + WT_BYTES + QKV_BYTES);
    short* vb = (short*)(ws + WT_BYTES + 2 * QKV_BYTES);
    char*  mlp = ws + WT_BYTES + 3 * QKV_BYTES;
    char*  opp = mlp + ML_BYTES;

    wprep_kernel<<<48, 256, 0, stream>>>(wq, wk, wv, Wt);
    qkv_proj_kernel<<<256, 512, 0, stream>>>(x, Wt, qb, kb, vb);
    attn_kernel<<<640, 256, 0, stream>>>(qb, kb, vb,
            (short*)opp, (float*)mlp, out);
    combine_kernel<<<384, 256, 0, stream>>>((const short*)opp,
            (const float*)mlp, out);
}

// Round 18
// 60.471 us; speedup vs baseline: 1.1463x; 1.0013x over previous
//
#include <hip/hip_runtime.h>
#include <hip/hip_bf16.h>

#define B_ 8
#define S_ 2048
#define E_ 1024
#define H_ 64
#define LOG2E 1.4426950408889634f

typedef __attribute__((ext_vector_type(8))) short short8;
typedef __attribute__((ext_vector_type(4))) float floatx4;
typedef unsigned int u32;

static __device__ __forceinline__ short f2bf(float f) {
    union { float f; unsigned u; } a; a.f = f;
    unsigned r = a.u + 0x7FFF + ((a.u >> 16) & 1);
    return (short)(r >> 16);
}
static __device__ __forceinline__ float bf2f(short s) {
    union { unsigned u; float f; } a; a.u = ((u32)(unsigned short)s) << 16;
    return a.f;
}
static __device__ __forceinline__ void gl_lds16(const void* g, void* l) {
    __builtin_amdgcn_global_load_lds(
        (const __attribute__((address_space(1))) u32*)(g),
        (__attribute__((address_space(3))) u32*)(l),
        16, 0, 0);
}

// ---------------------------------------------------------------------------
// Kernel 1: weights -> bf16, tiled per K-panel [16][192][64] with XOR chunk
// swizzle pre-applied in global.
// ---------------------------------------------------------------------------
__global__ __launch_bounds__(256) void wprep_kernel(
        const float* __restrict__ wq, const float* __restrict__ wk,
        const float* __restrict__ wv, short* __restrict__ Wt) {
    __shared__ short Ws[64][73];
    int bid = blockIdx.x;
    int m  = bid >> 4;
    int ec = bid & 15;
    const float* src = (m == 0) ? wq : ((m == 1) ? wk : wv);
    int t = threadIdx.x;
    {
        int er = t >> 2;
        int hc = (t & 3) * 16;
        const float* sp = src + (size_t)(ec * 64 + er) * H_ + hc;
        floatx4 v0 = *(const floatx4*)(sp);
        floatx4 v1 = *(const floatx4*)(sp + 4);
        floatx4 v2 = *(const floatx4*)(sp + 8);
        floatx4 v3 = *(const floatx4*)(sp + 12);
#pragma unroll
        for (int j = 0; j < 4; j++) Ws[er][hc + j]      = f2bf(v0[j]);
#pragma unroll
        for (int j = 0; j < 4; j++) Ws[er][hc + 4 + j]  = f2bf(v1[j]);
#pragma unroll
        for (int j = 0; j < 4; j++) Ws[er][hc + 8 + j]  = f2bf(v2[j]);
#pragma unroll
        for (int j = 0; j < 4; j++) Ws[er][hc + 12 + j] = f2bf(v3[j]);
    }
    __syncthreads();
    {
        int h  = t >> 2;
        int eo = (t & 3) * 16;
        int row = m * 64 + h;
        short* obase = Wt + (size_t)ec * 12288 + (size_t)row * 64;
#pragma unroll
        for (int g = 0; g < 2; g++) {
            short8 o;
#pragma unroll
            for (int jj = 0; jj < 8; jj++) o[jj] = Ws[eo + g * 8 + jj][h];
            int chunk = ((eo >> 3) + g) ^ (row & 7);
            *(short8*)(obase + chunk * 8) = o;
        }
    }
}

// ---------------------------------------------------------------------------
// Kernel 2: QKV projection GEMM (r10 version — best measured).
// BK=128, BM=64, grid 256, 512 thr = 8 waves (2 row x 4 col).
// ---------------------------------------------------------------------------
struct StageRegs {
    floatx4 x0, x1, x2, x3;
    short8 w0, w1, w2, w3, w4, w5;
};

__global__ __launch_bounds__(512, 2) void qkv_proj_kernel(
        const float* __restrict__ x, const short* __restrict__ Wt,
        short* __restrict__ qb, short* __restrict__ kb, short* __restrict__ vb) {
    __shared__ __align__(16) short Wlds[2][24576];
    __shared__ __align__(16) short Xlds[2][8704];

    int tid  = threadIdx.x;
    int lane = tid & 63;
    int w    = tid >> 6;
    int lrow = lane & 15;
    int lgrp = lane >> 4;

    int wr = w & 1;
    int wc = w >> 1;
    int rowbase = blockIdx.x * 64;

    int xr = tid >> 3;
    int xc = tid & 7;
    const float* xgp = x + (size_t)(rowbase + xr) * E_ + xc * 16;
    const short* wgp = Wt + (size_t)tid * 8;

    floatx4 acc0[3], acc1[3];
#pragma unroll
    for (int i = 0; i < 3; i++) {
        acc0[i] = (floatx4){0.f, 0.f, 0.f, 0.f};
        acc1[i] = (floatx4){0.f, 0.f, 0.f, 0.f};
    }

    StageRegs A, B;

#define LOADST(R, S) do {                                                    \
        const float* xn = xgp + (S) * 128;                                   \
        R.x0 = *(const floatx4*)(xn);                                        \
        R.x1 = *(const floatx4*)(xn + 4);                                    \
        R.x2 = *(const floatx4*)(xn + 8);                                    \
        R.x3 = *(const floatx4*)(xn + 12);                                   \
        const short* wn = wgp + (size_t)(S) * 24576;                         \
        R.w0 = *(const short8*)(wn);                                         \
        R.w1 = *(const short8*)(wn + 4096);                                  \
        R.w2 = *(const short8*)(wn + 8192);                                  \
        R.w3 = *(const short8*)(wn + 12288);                                 \
        R.w4 = *(const short8*)(wn + 16384);                                 \
        R.w5 = *(const short8*)(wn + 20480);                                 \
    } while (0)

#define WRITEST(R, BUF) do {                                                 \
        short8 xs0, xs1;                                                     \
        xs0[0] = f2bf(R.x0[0]); xs0[1] = f2bf(R.x0[1]);                      \
        xs0[2] = f2bf(R.x0[2]); xs0[3] = f2bf(R.x0[3]);                      \
        xs0[4] = f2bf(R.x1[0]); xs0[5] = f2bf(R.x1[1]);                      \
        xs0[6] = f2bf(R.x1[2]); xs0[7] = f2bf(R.x1[3]);                      \
        xs1[0] = f2bf(R.x2[0]); xs1[1] = f2bf(R.x2[1]);                      \
        xs1[2] = f2bf(R.x2[2]); xs1[3] = f2bf(R.x2[3]);                      \
        xs1[4] = f2bf(R.x3[0]); xs1[5] = f2bf(R.x3[1]);                      \
        xs1[6] = f2bf(R.x3[2]); xs1[7] = f2bf(R.x3[3]);                      \
        *(short8*)&Xlds[BUF][xr * 136 + xc * 16]     = xs0;                  \
        *(short8*)&Xlds[BUF][xr * 136 + xc * 16 + 8] = xs1;                  \
        short* lw = &Wlds[BUF][tid * 8];                                     \
        *(short8*)(lw)         = R.w0;                                       \
        *(short8*)(lw + 4096)  = R.w1;                                       \
        *(short8*)(lw + 8192)  = R.w2;                                       \
        *(short8*)(lw + 12288) = R.w3;                                       \
        *(short8*)(lw + 16384) = R.w4;                                       \
        *(short8*)(lw + 20480) = R.w5;                                       \
    } while (0)

#define COMPUTE(BUF) do {                                                    \
        const short* xb0 = &Xlds[BUF][(wr * 32 + lrow) * 136 + lgrp * 8];    \
        const short* xb1 = xb0 + 16 * 136;                                   \
        short8 a00 = *(const short8*)(xb0);                                  \
        short8 a01 = *(const short8*)(xb0 + 32);                             \
        short8 a02 = *(const short8*)(xb0 + 64);                             \
        short8 a03 = *(const short8*)(xb0 + 96);                             \
        short8 a10 = *(const short8*)(xb1);                                  \
        short8 a11 = *(const short8*)(xb1 + 32);                             \
        short8 a12 = *(const short8*)(xb1 + 64);                             \
        short8 a13 = *(const short8*)(xb1 + 96);                             \
        _Pragma("unroll")                                                    \
        for (int nf = 0; nf < 3; nf++) {                                     \
            int row = wc * 48 + nf * 16 + lrow;                              \
            int c0  = lgrp ^ (row & 7);                                      \
            const short* wb = &Wlds[BUF][row * 64];                          \
            short8 b0 = *(const short8*)(wb + c0 * 8);                       \
            short8 b1 = *(const short8*)(wb + (c0 ^ 4) * 8);                 \
            short8 b2 = *(const short8*)(wb + 12288 + c0 * 8);               \
            short8 b3 = *(const short8*)(wb + 12288 + (c0 ^ 4) * 8);         \
            acc0[nf] = __builtin_amdgcn_mfma_f32_16x16x32_bf16(a00, b0, acc0[nf], 0, 0, 0); \
            acc0[nf] = __builtin_amdgcn_mfma_f32_16x16x32_bf16(a01, b1, acc0[nf], 0, 0, 0); \
            acc0[nf] = __builtin_amdgcn_mfma_f32_16x16x32_bf16(a02, b2, acc0[nf], 0, 0, 0); \
            acc0[nf] = __builtin_amdgcn_mfma_f32_16x16x32_bf16(a03, b3, acc0[nf], 0, 0, 0); \
            acc1[nf] = __builtin_amdgcn_mfma_f32_16x16x32_bf16(a10, b0, acc1[nf], 0, 0, 0); \
            acc1[nf] = __builtin_amdgcn_mfma_f32_16x16x32_bf16(a11, b1, acc1[nf], 0, 0, 0); \
            acc1[nf] = __builtin_amdgcn_mfma_f32_16x16x32_bf16(a12, b2, acc1[nf], 0, 0, 0); \
            acc1[nf] = __builtin_amdgcn_mfma_f32_16x16x32_bf16(a13, b3, acc1[nf], 0, 0, 0); \
        }                                                                    \
    } while (0)

    LOADST(B, 0);
    WRITEST(B, 0);
    LOADST(A, 1);
    __syncthreads();

    for (int s = 0; s < 8; s += 2) {
        COMPUTE(0);
        WRITEST(A, 1);
        if (s + 2 < 8) LOADST(B, s + 2);
        __syncthreads();
        COMPUTE(1);
        if (s + 2 < 8) WRITEST(B, 0);
        if (s + 3 < 8) LOADST(A, s + 3);
        __syncthreads();
    }
#undef LOADST
#undef WRITEST
#undef COMPUTE

    {
#pragma unroll
        for (int nf = 0; nf < 3; nf++)
#pragma unroll
            for (int j = 0; j < 4; j++) {
                Wlds[0][(w * 2 + 0) * 896 + (lgrp * 4 + j) * 56 + nf * 16 + lrow] = f2bf(acc0[nf][j]);
                Wlds[0][(w * 2 + 1) * 896 + (lgrp * 4 + j) * 56 + nf * 16 + lrow] = f2bf(acc1[nf][j]);
            }
        __syncthreads();
#pragma unroll
        for (int k = 0; k < 3; k++) {
            int id   = tid + k * 512;
            int slab = id / 96;
            int rem  = id % 96;
            int rloc = rem / 6;
            int cm   = rem % 6;
            int w2  = slab >> 1;
            int rh  = slab & 1;
            int swr = w2 & 1;
            int swc = w2 >> 1;
            short8 v = *(const short8*)&Wlds[0][slab * 896 + rloc * 56 + cm * 8];
            int grow = rowbase + swr * 32 + rh * 16 + rloc;
            int gcol = swc * 48 + cm * 8;
            short* dst = (gcol < 64) ? qb : ((gcol < 128) ? kb : vb);
            *(short8*)(dst + (size_t)grow * H_ + (gcol & 63)) = v;
        }
    }
}

// ---------------------------------------------------------------------------
// Kernel 3: causal flash attention (KVBLK=64, Klds staged, 4 waves x 16
// q-rows), FINE adaptive split: <=4 KV-tiles per split, balanced chunking.
// Units per batch = sum_qt ceil((qt+1)/4) = 144; grid = 8 x 144 = 1152.
// Group g = qt>>2 (ns = g+1 splits); unit base for group g = 2g(g+1).
// g==0 (q<256): single split -> normalized f32 direct to out.
// ---------------------------------------------------------------------------
__global__ __launch_bounds__(256) void attn_kernel(
        const short* __restrict__ qb, const short* __restrict__ kb,
        const short* __restrict__ vb, short* __restrict__ Opart,
        float* __restrict__ ml, float* __restrict__ out) {
    __shared__ __align__(16) short Klds[2][4096];
    __shared__ __align__(16) short Vt[64][72];
    __shared__ __align__(16) short Ps[4][16][72];

    int tid  = threadIdx.x;
    int lane = tid & 63;
    int w    = tid >> 6;
    int lrow = lane & 15;
    int lgrp = lane >> 4;
    int lk   = lgrp * 8;

    int idx = 1151 - (int)blockIdx.x;
    int b    = idx / 144;
    int r144 = idx - b * 144;
    int g;
    if      (r144 < 4)   g = 0;
    else if (r144 < 12)  g = 1;
    else if (r144 < 24)  g = 2;
    else if (r144 < 40)  g = 3;
    else if (r144 < 60)  g = 4;
    else if (r144 < 84)  g = 5;
    else if (r144 < 112) g = 6;
    else                 g = 7;
    int base0 = 2 * g * (g + 1);
    int gp1  = g + 1;
    int r    = r144 - base0;
    int qloc = r / gp1;
    int sp   = r - qloc * gp1;
    int qt   = g * 4 + qloc;
    int q0   = qt * 64;
    int T    = qt + 1;
    int cbase = T / gp1;
    int crem  = T % gp1;
    int t0 = sp * cbase + ((sp < crem) ? sp : crem);
    int t1 = t0 + cbase + ((sp < crem) ? 1 : 0);

    const short* kbase = kb + (size_t)b * S_ * H_;
    const short* vbase = vb + (size_t)b * S_ * H_;

    int qrow = q0 + w * 16 + lrow;
    const short* qptr = qb + ((size_t)b * S_ + qrow) * H_;
    short8 qf0 = *(const short8*)(qptr + lk);
    short8 qf1 = *(const short8*)(qptr + 32 + lk);

#define STAGE_K(TT, BUF) do {                                                 \
        int kv0s = (TT) * 64;                                                 \
        _Pragma("unroll")                                                     \
        for (int it = 0; it < 2; it++) {                                      \
            int j = it * 256 + w * 64 + lane;                                 \
            int rr = j >> 3; int c = j & 7;                                   \
            const short* pk = kbase + (size_t)(kv0s + rr) * H_ +              \
                              ((c ^ (rr & 7)) << 3);                          \
            short* lkp = &Klds[BUF][(it * 256 + w * 64) * 8];                 \
            gl_lds16(pk, lkp);                                                \
        } } while (0)

    int kvr = tid >> 2;
    int hs  = (tid & 3) * 16;

    STAGE_K(t0, 0);
    const short* vp0 = vbase + (size_t)(t0 * 64 + kvr) * H_ + hs;
    short8 vr0 = *(const short8*)vp0;
    short8 vr1 = *(const short8*)(vp0 + 8);

    floatx4 O[4];
#pragma unroll
    for (int nf = 0; nf < 4; nf++) O[nf] = (floatx4){0.f, 0.f, 0.f, 0.f};
    float m[4], lsum[4];
#pragma unroll
    for (int j = 0; j < 4; j++) { m[j] = -1e30f; lsum[j] = 0.f; }

    for (int t = t0; t < t1; t++) {
        int cur = (t - t0) & 1;
        int kv0 = t * 64;
        __syncthreads();

        if (t + 1 < t1) STAGE_K(t + 1, cur ^ 1);

#pragma unroll
        for (int c = 0; c < 8; c++) Vt[hs + c][kvr] = vr0[c];
#pragma unroll
        for (int c = 0; c < 8; c++) Vt[hs + 8 + c][kvr] = vr1[c];

        if (t + 1 < t1) {
            const short* vp = vbase + (size_t)((t + 1) * 64 + kvr) * H_ + hs;
            vr0 = *(const short8*)vp;
            vr1 = *(const short8*)(vp + 8);
        }

        floatx4 s[4];
#pragma unroll
        for (int nf = 0; nf < 4; nf++) {
            int rr = nf * 16 + lrow;
            int c0 = lgrp ^ (rr & 7);
            const short* kp = &Klds[cur][rr * 64];
            short8 b0 = *(const short8*)(kp + c0 * 8);
            short8 b1 = *(const short8*)(kp + (c0 ^ 4) * 8);
            floatx4 a = (floatx4){0.f, 0.f, 0.f, 0.f};
            a = __builtin_amdgcn_mfma_f32_16x16x32_bf16(qf0, b0, a, 0, 0, 0);
            a = __builtin_amdgcn_mfma_f32_16x16x32_bf16(qf1, b1, a, 0, 0, 0);
            s[nf] = a;
        }
#pragma unroll
        for (int nf = 0; nf < 4; nf++)
#pragma unroll
            for (int j = 0; j < 4; j++) s[nf][j] *= 0.03125f;

        if (t == qt) {
#pragma unroll
            for (int nf = 0; nf < 4; nf++) {
                int kvidx = kv0 + nf * 16 + lrow;
#pragma unroll
                for (int j = 0; j < 4; j++) {
                    int qidx = q0 + w * 16 + lgrp * 4 + j;
                    if (kvidx > qidx) s[nf][j] = -1e30f;
                }
            }
        }

        float alpha[4];
#pragma unroll
        for (int j = 0; j < 4; j++) {
            float mx = fmaxf(fmaxf(s[0][j], s[1][j]), fmaxf(s[2][j], s[3][j]));
#pragma unroll
            for (int off = 1; off < 16; off <<= 1)
                mx = fmaxf(mx, __shfl_xor(mx, off));
            float mn = fmaxf(m[j], mx);
            alpha[j] = exp2f((m[j] - mn) * LOG2E);
            m[j] = mn;
            float ps = 0.f;
#pragma unroll
            for (int nf = 0; nf < 4; nf++) {
                float p = exp2f((s[nf][j] - mn) * LOG2E);
                s[nf][j] = p;
                ps += p;
            }
#pragma unroll
            for (int off = 1; off < 16; off <<= 1)
                ps += __shfl_xor(ps, off);
            lsum[j] = lsum[j] * alpha[j] + ps;
        }

#pragma unroll
        for (int nf = 0; nf < 4; nf++) {
#pragma unroll
            for (int j = 0; j < 4; j++) {
                Ps[w][lgrp * 4 + j][nf * 16 + lrow] = f2bf(s[nf][j]);
                O[nf][j] *= alpha[j];
            }
        }
        __syncthreads();

        short8 pa0 = *(const short8*)&Ps[w][lrow][lk];
        short8 pa1 = *(const short8*)&Ps[w][lrow][32 + lk];
#pragma unroll
        for (int nf = 0; nf < 4; nf++) {
            short8 vb0 = *(const short8*)&Vt[nf * 16 + lrow][lk];
            short8 vb1 = *(const short8*)&Vt[nf * 16 + lrow][32 + lk];
            O[nf] = __builtin_amdgcn_mfma_f32_16x16x32_bf16(pa0, vb0, O[nf], 0, 0, 0);
            O[nf] = __builtin_amdgcn_mfma_f32_16x16x32_bf16(pa1, vb1, O[nf], 0, 0, 0);
        }
    }
#undef STAGE_K

    if (g == 0) {
#pragma unroll
        for (int nf = 0; nf < 4; nf++)
#pragma unroll
            for (int j = 0; j < 4; j++) {
                size_t grow = (size_t)b * S_ + q0 + w * 16 + lgrp * 4 + j;
                out[grow * H_ + nf * 16 + lrow] = O[nf][j] / lsum[j];
            }
        return;
    }

    size_t mlrow = (size_t)sp * 16384 + (size_t)b * S_ + q0 + w * 16 + lgrp * 4;
    if (lrow == 0) {
#pragma unroll
        for (int j = 0; j < 4; j++) {
            ml[(mlrow + j) * 2 + 0] = m[j];
            ml[(mlrow + j) * 2 + 1] = lsum[j];
        }
    }
    __syncthreads();
#pragma unroll
    for (int nf = 0; nf < 4; nf++)
#pragma unroll
        for (int j = 0; j < 4; j++)
            Ps[w][lgrp * 4 + j][nf * 16 + lrow] = f2bf(O[nf][j]);
    __syncthreads();
    {
        int row = lane >> 2;
        int c   = lane & 3;
        short8 ov0 = *(const short8*)&Ps[w][row][c * 16];
        short8 ov1 = *(const short8*)&Ps[w][row][c * 16 + 8];
        size_t grow = (size_t)sp * 16384 + (size_t)b * S_ + q0 + w * 16 + row;
        *(short8*)(Opart + grow * H_ + c * 16) = ov0;
        *(short8*)(Opart + grow * H_ + c * 16 + 8) = ov1;
    }
}

// ---------------------------------------------------------------------------
// Kernel 4: combine partials for rows q >= 256 — vectorized (G13).
// 8 threads per row, each owns 8 h.  14336 rows -> 448 blocks.
// nact = (qt>>2)+1, qt = q>>6  (2..8).
// ---------------------------------------------------------------------------
__global__ __launch_bounds__(256) void combine_kernel(
        const short* __restrict__ Opart, const float* __restrict__ ml,
        float* __restrict__ out) {
    int t = threadIdx.x;
    int rr = blockIdx.x * 32 + (t >> 3);   // 0..14335
    int hc = (t & 7) * 8;
    int b = rr / 1792;
    int q = 256 + (rr - b * 1792);
    size_t row = (size_t)b * S_ + q;
    int nact = ((q >> 6) >> 2) + 1;        // 2..8

    float M = -1e30f;
    for (int s = 0; s < nact; s++)
        M = fmaxf(M, ml[((size_t)s * 16384 + row) * 2]);

    float L = 0.f;
    float acc[8];
#pragma unroll
    for (int i = 0; i < 8; i++) acc[i] = 0.f;
    for (int s = 0; s < nact; s++) {
        float ms = ml[((size_t)s * 16384 + row) * 2];
        float ls = ml[((size_t)s * 16384 + row) * 2 + 1];
        float wgt = exp2f((ms - M) * LOG2E);
        L += wgt * ls;
        short8 ov = *(const short8*)(Opart + ((size_t)s * 16384 + row) * H_ + hc);
#pragma unroll
        for (int i = 0; i < 8; i++) acc[i] += wgt * bf2f(ov[i]);
    }
    float invL = 1.f / L;
    floatx4 o0, o1;
#pragma unroll
    for (int i = 0; i < 4; i++) { o0[i] = acc[i] * invL; o1[i] = acc[4 + i] * invL; }
    float* op = out + row * H_ + hc;
    *(floatx4*)op = o0;
    *(floatx4*)(op + 4) = o1;
}

// ---------------------------------------------------------------------------
extern "C" void kernel_launch(void* const* d_in, const int* in_sizes, int n_in,
                              void* d_out, int out_size, void* d_ws, size_t ws_size,
                              hipStream_t stream) {
    const float* x  = (const float*)d_in[0];
    const float* wq = (const float*)d_in[1];
    const float* wk = (const float*)d_in[2];
    const float* wv = (const float*)d_in[3];
    float* out = (float*)d_out;

    char* ws = (char*)d_ws;
    const size_t WT_BYTES  = (size_t)192 * 1024 * 2;            // 384 KB
    const size_t QKV_BYTES = (size_t)B_ * S_ * H_ * 2;          // 2 MB each
    const size_t ML_BYTES  = (size_t)8 * 16384 * 2 * 4;         // 1 MB (8 splits)

    short* Wt = (short*)ws;
    short* qb = (short*)(ws + WT_BYTES);
    short* kb = (short*)(ws + WT_BYTES + QKV_BYTES);
    short* vb = (short*)(ws + WT_BYTES + 2 * QKV_BYTES);
    char*  mlp = ws + WT_BYTES + 3 * QKV_BYTES;
    char*  opp = mlp + ML_BYTES;                                // 8 x 2 MB bf16

    wprep_kernel<<<48, 256, 0, stream>>>(wq, wk, wv, Wt);
    qkv_proj_kernel<<<256, 512, 0, stream>>>(x, Wt, qb, kb, vb);
    attn_kernel<<<1152, 256, 0, stream>>>(qb, kb, vb,
            (short*)opp, (float*)mlp, out);
    combine_kernel<<<448, 256, 0, stream>>>((const short*)opp,
            (const float*)mlp, out);
}